// Round 9
// baseline (343.966 us; speedup 1.0000x reference)
//
#include <hip/hip_runtime.h>
#include <cstddef>

#define B_ 32
#define C_ 32
#define L_ 16384
#define H_ 4
#define DH_ 8
#define NB_ 3
#define DOUT_ 10
#define SEG_ 256
#define S_ (L_/SEG_)   // 64 segments == 64 block tiles

#define TILE 256
#define AST  40    // A_lds row stride (halfs): 80 B/row -> 16B-aligned b128 frag reads
#define OST  260   // O16 row stride (floats): multiple of 4 -> aligned f32x4 writes

typedef _Float16 f16_t;
typedef _Float16 f16x2 __attribute__((ext_vector_type(2)));
typedef _Float16 f16x8 __attribute__((ext_vector_type(8)));
typedef float    f32x4 __attribute__((ext_vector_type(4)));

// Branch-free gelu via Abramowitz-Stegun 7.1.26 erf approximation (|eps|<=1.5e-7).
__device__ __forceinline__ float gelu_f(float x){
    const float z  = fabsf(x) * 0.70710678118654752440f;
    const float t  = __builtin_amdgcn_rcpf(fmaf(0.3275911f, z, 1.0f));
    const float e  = __expf(-z * z);
    float p = fmaf(t, 1.061405429f, -1.453152027f);
    p = fmaf(t, p, 1.421413741f);
    p = fmaf(t, p, -0.284496736f);
    p = fmaf(t, p, 0.254829592f);
    const float erfz = 1.0f - p * t * e;          // erf(|x|/sqrt(2))
    const float phi  = fmaf(copysignf(erfz, x), 0.5f, 0.5f);
    return x * phi;
}

// ---- stats (input x only): per (b, head, seg) partial max/sumexp/kv over 256 pos ----
// Also zeroes `pooled` (kernel boundary orders this before block2's atomics),
// removing the hipMemset dispatch.
__global__ __launch_bounds__(256) void stats_kernel(const float* __restrict__ h,
                                                    float* __restrict__ part,
                                                    float* __restrict__ pooled){
    const int seg = blockIdx.x;
    const int hd  = blockIdx.y;
    const int b   = blockIdx.z;
    const int t   = threadIdx.x;
    const int d   = t >> 5;   // 0..7; wave-half owns one d
    const int j   = t & 31;

    if (seg == 0 && hd == 0 && b == 0){
        for (int i = t; i < B_*C_; i += 256) pooled[i] = 0.0f;
    }

    __shared__ float tile[8][SEG_];   // 8 KB
    __shared__ float sm[8];

    const float* hb = h + (size_t)b * ((size_t)C_*L_) + (size_t)(hd*DH_)*L_ + (size_t)seg*SEG_;

    for (int f = t; f < 8*SEG_/4; f += 256){
        const int row = f >> 6;            // 64 float4 per row
        const int c4  = (f & 63) << 2;
        *(f32x4*)&tile[row][c4] = *(const f32x4*)&hb[(size_t)row*L_ + c4];
    }
    __syncthreads();

    float m = -INFINITY;
    #pragma unroll
    for (int i = 0; i < SEG_/32; i++) m = fmaxf(m, tile[d][j + 32*i]);
    m = fmaxf(m, __shfl_xor(m, 1));
    m = fmaxf(m, __shfl_xor(m, 2));
    m = fmaxf(m, __shfl_xor(m, 4));
    m = fmaxf(m, __shfl_xor(m, 8));
    m = fmaxf(m, __shfl_xor(m, 16));
    if (j == 0) sm[d] = m;
    const float m_d = m;

    float s = 0.0f;
    float kv[8];
    #pragma unroll
    for (int e = 0; e < 8; e++) kv[e] = 0.0f;
    #pragma unroll
    for (int i = 0; i < SEG_/32; i++){
        const int k = j + 32*i;
        const float ek = __expf(tile[d][k] - m_d);
        s += ek;
        #pragma unroll
        for (int e = 0; e < 8; e++) kv[e] = fmaf(ek, tile[e][k], kv[e]);
    }
    s += __shfl_xor(s, 1);  s += __shfl_xor(s, 2);  s += __shfl_xor(s, 4);
    s += __shfl_xor(s, 8);  s += __shfl_xor(s, 16);
    #pragma unroll
    for (int e = 0; e < 8; e++){
        kv[e] += __shfl_xor(kv[e], 1);  kv[e] += __shfl_xor(kv[e], 2);
        kv[e] += __shfl_xor(kv[e], 4);  kv[e] += __shfl_xor(kv[e], 8);
        kv[e] += __shfl_xor(kv[e], 16);
    }
    __syncthreads();

    float* po = part + (size_t)((b*H_ + hd)*S_ + seg) * 80;
    if (j == 0){
        po[8 + d] = s;
        #pragma unroll
        for (int e = 0; e < 8; e++) po[16 + d*8 + e] = kv[e];
    }
    if (t < 8) po[t] = sm[t];
}

// ---- block: fused merge (prologue) + attention (fp32) + FC1/FC2 (f16 MFMA)
//      + fused next-block stats (epilogue) ----
// Merge prologue: every WG redundantly computes its batch's kvn[4][8][8] from
// part_in (64 records/head, L2-hot) into LDS -> deletes the 3 merge_kernel
// launches (R8: 11-dispatch serial chain; ~10 us launch+gap each).
// part is double-buffered by the caller (read part_in / write part_out race
// otherwise: a fast WG's epilogue could clobber records a slow WG's prologue
// hasn't read yet).
// waves_per_eu(3,8): budget from min=3 (~168 VGPR, kernel uses ~68); max=8
// stops the R8 (3,4) attr from capping residency below the LDS limit.
template<bool LAST>
__global__ __launch_bounds__(256)
__attribute__((amdgpu_waves_per_eu(3, 8)))
void block_kernel(const float* hin,
                  float* hout,
                  const float* __restrict__ part_in,
                  const float* __restrict__ W1,
                  const float* __restrict__ b1,
                  const float* __restrict__ W2,
                  const float* __restrict__ b2,
                  float* __restrict__ part_out,
                  float* __restrict__ pooled){
    __shared__ __align__(16) char uni[TILE*AST*2];   // 20480 B: Ash, then O16
    f16_t* Ash = (f16_t*)uni;            // [pos][k], stride AST halfs
    float* O16 = (float*)uni;            // 16 x OST floats (16640 B)
    __shared__ f16_t Bsh1[32*AST];       // 2560 B: W1 as [n][k]
    __shared__ f16_t Bsh2[32*AST];       // 2560 B
    __shared__ float sb1[32], sb2[32];
    __shared__ float skv[256];           // kvn[head][d][e]
    __shared__ float pool[32];

    const int tid = threadIdx.x;
    const int b   = blockIdx.y;
    const int l0  = blockIdx.x * TILE;
    const int l   = l0 + tid;
    const size_t base = (size_t)b * ((size_t)C_*L_);

    // stage weights f32->f16 into B-layout: Bsh[n][k] = W[k*32+n]
    for (int i = tid; i < 1024; i += 256){
        const int k = i >> 5, n = i & 31;
        Bsh1[n*AST + k] = (f16_t)W1[i];
        Bsh2[n*AST + k] = (f16_t)W2[i];
    }
    if (tid < 32){ sb1[tid] = b1[tid]; sb2[tid] = b2[tid]; }
    if (LAST && tid < 32) pool[tid] = 0.0f;

    // ---- fused merge: kvn for batch b -> skv ----
    {
        const int head = tid >> 6;       // 0..3 (one head per wave)
        const int de   = tid & 63;       // (d,e)
        const int dd   = de >> 3;
        const float* p = part_in + (size_t)(b*H_ + head) * S_ * 80;
        float M = -INFINITY;
        #pragma unroll 4
        for (int s2 = 0; s2 < S_; s2++) M = fmaxf(M, p[s2*80 + dd]);
        float ssum = 0.f, kvsum = 0.f;
        #pragma unroll 4
        for (int s2 = 0; s2 < S_; s2++){
            const float sc = __expf(p[s2*80 + dd] - M);
            ssum  = fmaf(p[s2*80 + 8 + dd], sc, ssum);
            kvsum = fmaf(p[s2*80 + 16 + de], sc, kvsum);
        }
        skv[head*64 + de] = kvsum * __builtin_amdgcn_rcpf(ssum);
    }
    __syncthreads();   // skv (and weights) visible

    // ---- phase 1: per-thread fp32 attention ----
    float h[32];
    #pragma unroll
    for (int c = 0; c < 32; c++) h[c] = hin[base + (size_t)c*L_ + l];

    float attn[32];
    #pragma unroll
    for (int hh = 0; hh < 4; hh++){
        float mq = h[hh*8];
        #pragma unroll
        for (int d2 = 1; d2 < 8; d2++) mq = fmaxf(mq, h[hh*8 + d2]);
        float es[8]; float qs = 0.f;
        #pragma unroll
        for (int d2 = 0; d2 < 8; d2++){ es[d2] = __expf(h[hh*8 + d2] - mq); qs += es[d2]; }
        const float inv = __builtin_amdgcn_rcpf(qs);
        #pragma unroll
        for (int e = 0; e < 8; e++){
            float a = 0.f;
            #pragma unroll
            for (int d2 = 0; d2 < 8; d2++) a += es[d2] * skv[hh*64 + d2*8 + e];
            attn[hh*8 + e] = a * inv;
        }
    }

    // attn -> f16 A matrix in LDS: Ash[pos=tid][k]
    #pragma unroll
    for (int k2 = 0; k2 < 32; k2 += 2){
        f16x2 pr = { (f16_t)attn[k2], (f16_t)attn[k2+1] };
        *(f16x2*)&Ash[tid*AST + k2] = pr;
    }
    __syncthreads();

    // ---- phase 2: MFMA FCs ----
    const int wv   = tid >> 6;
    const int lane = tid & 63;
    const int lr   = lane & 15;
    const int lk   = lane >> 4;
    const f32x4 zero = {0.f, 0.f, 0.f, 0.f};

    f16x8 a[4], bw[2];
    f32x4 d[8];

    // FC1
    #pragma unroll
    for (int mt = 0; mt < 4; mt++)
        a[mt] = *(const f16x8*)&Ash[(wv*64 + mt*16 + lr)*AST + lk*8];
    #pragma unroll
    for (int nt = 0; nt < 2; nt++)
        bw[nt] = *(const f16x8*)&Bsh1[(nt*16 + lr)*AST + lk*8];
    #pragma unroll
    for (int nt = 0; nt < 2; nt++)
        #pragma unroll
        for (int mt = 0; mt < 4; mt++)
            d[nt*4+mt] = __builtin_amdgcn_mfma_f32_16x16x32_f16(a[mt], bw[nt], zero, 0, 0, 0);

    // bias + gelu + write back as A2 (in-place; rows are wave-private)
    #pragma unroll
    for (int nt = 0; nt < 2; nt++){
        const float bias = sb1[nt*16 + lr];
        #pragma unroll
        for (int mt = 0; mt < 4; mt++){
            #pragma unroll
            for (int r = 0; r < 4; r++){
                const float v = gelu_f(d[nt*4+mt][r] + bias);
                Ash[(wv*64 + mt*16 + lk*4 + r)*AST + (nt*16 + lr)] = (f16_t)v;
            }
        }
    }
    __syncthreads();

    // FC2
    #pragma unroll
    for (int mt = 0; mt < 4; mt++)
        a[mt] = *(const f16x8*)&Ash[(wv*64 + mt*16 + lr)*AST + lk*8];
    #pragma unroll
    for (int nt = 0; nt < 2; nt++)
        bw[nt] = *(const f16x8*)&Bsh2[(nt*16 + lr)*AST + lk*8];
    #pragma unroll
    for (int nt = 0; nt < 2; nt++)
        #pragma unroll
        for (int mt = 0; mt < 4; mt++)
            d[nt*4+mt] = __builtin_amdgcn_mfma_f32_16x16x32_f16(a[mt], bw[nt], zero, 0, 0, 0);

    // bias + gelu on D (fp32)
    #pragma unroll
    for (int nt = 0; nt < 2; nt++){
        const float bias = sb2[nt*16 + lr];
        #pragma unroll
        for (int mt = 0; mt < 4; mt++)
            #pragma unroll
            for (int r = 0; r < 4; r++)
                d[nt*4+mt][r] = gelu_f(d[nt*4+mt][r] + bias);
    }

    if (!LAST){
        const int row16 = tid >> 4;      // 0..15: local channel row in this half
        const int grp   = tid & 15;      // 16 threads per row
        #pragma unroll
        for (int nt = 0; nt < 2; nt++){
            __syncthreads();   // Ash fully read (nt=0) / prev O16 consumed (nt=1)
            #pragma unroll
            for (int mt = 0; mt < 4; mt++)
                *(f32x4*)&O16[lr*OST + wv*64 + mt*16 + lk*4] = d[nt*4+mt];
            __syncthreads();
            #pragma unroll
            for (int c = 0; c < 16; c++)
                hout[base + (size_t)(nt*16 + c)*L_ + l0 + tid] = O16[c*OST + tid];

            // fused stats for the NEXT block: this half = heads nt*2 + {0,1}
            const int head = nt*2 + (row16 >> 3);
            const int dd   = row16 & 7;
            const float* rowD = &O16[row16*OST];
            const float* rowE = &O16[(row16 & 8)*OST];
            float m = -INFINITY;
            #pragma unroll
            for (int i = 0; i < 16; i++) m = fmaxf(m, rowD[grp + 16*i]);
            m = fmaxf(m, __shfl_xor(m, 1)); m = fmaxf(m, __shfl_xor(m, 2));
            m = fmaxf(m, __shfl_xor(m, 4)); m = fmaxf(m, __shfl_xor(m, 8));
            float s = 0.f, kvp[8];
            #pragma unroll
            for (int e = 0; e < 8; e++) kvp[e] = 0.f;
            #pragma unroll
            for (int i = 0; i < 16; i++){
                const int k = grp + 16*i;
                const float ek = __expf(rowD[k] - m);
                s += ek;
                #pragma unroll
                for (int e = 0; e < 8; e++) kvp[e] = fmaf(ek, rowE[e*OST + k], kvp[e]);
            }
            s += __shfl_xor(s, 1); s += __shfl_xor(s, 2);
            s += __shfl_xor(s, 4); s += __shfl_xor(s, 8);
            #pragma unroll
            for (int e = 0; e < 8; e++){
                kvp[e] += __shfl_xor(kvp[e], 1); kvp[e] += __shfl_xor(kvp[e], 2);
                kvp[e] += __shfl_xor(kvp[e], 4); kvp[e] += __shfl_xor(kvp[e], 8);
            }
            if (grp == 0){
                float* po = part_out + (size_t)((b*H_ + head)*S_ + blockIdx.x) * 80;
                po[dd]     = m;
                po[8 + dd] = s;
                #pragma unroll
                for (int e = 0; e < 8; e++) po[16 + dd*8 + e] = kvp[e];
            }
        }
    } else {
        __syncthreads();   // pool[] initialized
        #pragma unroll
        for (int nt = 0; nt < 2; nt++){
            float ps = 0.f;
            #pragma unroll
            for (int mt = 0; mt < 4; mt++)
                ps += d[nt*4+mt][0] + d[nt*4+mt][1] + d[nt*4+mt][2] + d[nt*4+mt][3];
            atomicAdd(&pool[nt*16 + lr], ps);
        }
        __syncthreads();
        if (tid < 32) atomicAdd(&pooled[b*32 + tid], pool[tid]);
    }
}

// ---- head: pooled/L -> Wh+bh -> BN(eval) -> gelu -> Wf+bf ----
__global__ __launch_bounds__(1024) void head_kernel(const float* __restrict__ pooled,
                                                    const float* __restrict__ Wh,
                                                    const float* __restrict__ bh,
                                                    const float* __restrict__ gam,
                                                    const float* __restrict__ bet,
                                                    const float* __restrict__ mean,
                                                    const float* __restrict__ var,
                                                    const float* __restrict__ Wf,
                                                    const float* __restrict__ bf,
                                                    float* __restrict__ out){
    __shared__ float y2[32][32];
    const int t = threadIdx.x;      // 0..1023
    const int b = t >> 5, c = t & 31;
    float a = bh[c];
    const float invL = 1.0f / (float)L_;
    #pragma unroll
    for (int d = 0; d < 32; d++) a += (pooled[b*32 + d] * invL) * Wh[d*32 + c];
    a = (a - mean[c]) * rsqrtf(var[c] + 1e-5f) * gam[c] + bet[c];
    y2[b][c] = gelu_f(a);
    __syncthreads();
    if (t < B_*DOUT_){
        const int b2 = t / DOUT_, j = t % DOUT_;
        float r = bf[j];
        #pragma unroll
        for (int c2 = 0; c2 < 32; c2++) r += y2[b2][c2] * Wf[c2*DOUT_ + j];
        out[t] = r;
    }
}

extern "C" void kernel_launch(void* const* d_in, const int* in_sizes, int n_in,
                              void* d_out, int out_size, void* d_ws, size_t ws_size,
                              hipStream_t stream){
    (void)in_sizes; (void)n_in; (void)out_size; (void)ws_size;
    const float* x    = (const float*)d_in[0];
    const float* fW1  = (const float*)d_in[1];
    const float* fb1  = (const float*)d_in[2];
    const float* fW2  = (const float*)d_in[3];
    const float* fb2  = (const float*)d_in[4];
    const float* Wh   = (const float*)d_in[5];
    const float* bh   = (const float*)d_in[6];
    const float* gam  = (const float*)d_in[7];
    const float* bet  = (const float*)d_in[8];
    const float* mean = (const float*)d_in[9];
    const float* var  = (const float*)d_in[10];
    const float* Wf   = (const float*)d_in[11];
    const float* bf   = (const float*)d_in[12];
    float* out = (float*)d_out;

    float* hbuf   = (float*)d_ws;                          // B*C*L floats (64 MB)
    float* partA  = hbuf  + (size_t)B_*C_*L_;              // B*H*S*80 (~2.6 MB)
    float* partB  = partA + (size_t)B_*H_*S_*80;           // double buffer
    float* pooled = partB + (size_t)B_*H_*S_*80;           // B*C

    dim3 sgrid(S_, H_, B_);
    dim3 bgrid(L_/TILE, B_);

    // 5-dispatch chain: stats(x) -> block0 -> block1 -> block2 -> head
    stats_kernel<<<sgrid, 256, 0, stream>>>(x, partA, pooled);
    block_kernel<false><<<bgrid, 256, 0, stream>>>(x, hbuf, partA,
        fW1, fb1, fW2, fb2, partB, nullptr);
    block_kernel<false><<<bgrid, 256, 0, stream>>>(hbuf, hbuf, partB,
        fW1 + C_*C_, fb1 + C_, fW2 + C_*C_, fb2 + C_, partA, nullptr);
    block_kernel<true><<<bgrid, 256, 0, stream>>>(hbuf, nullptr, partA,
        fW1 + 2*C_*C_, fb1 + 2*C_, fW2 + 2*C_*C_, fb2 + 2*C_, nullptr, pooled);
    head_kernel<<<1, 1024, 0, stream>>>(pooled, Wh, bh, gam, bet, mean, var, Wf, bf, out);
}

// Round 10
// 290.953 us; speedup vs baseline: 1.1822x; 1.1822x over previous
//
#include <hip/hip_runtime.h>
#include <cstddef>

#define B_ 32
#define C_ 32
#define L_ 16384
#define H_ 4
#define DH_ 8
#define NB_ 3
#define DOUT_ 10
#define SEG_ 256
#define S_ (L_/SEG_)   // 64 segments == 64 block tiles

#define TILE 256
#define AST  40    // A_lds row stride (halfs): 80 B/row -> 16B-aligned b128 frag reads
#define OST  260   // O16 row stride (floats): multiple of 4 -> aligned f32x4 writes
#define SCST 9     // sc scratch stride (floats): spreads banks for per-lane 8-float rows

typedef _Float16 f16_t;
typedef _Float16 f16x2 __attribute__((ext_vector_type(2)));
typedef _Float16 f16x8 __attribute__((ext_vector_type(8)));
typedef float    f32x4 __attribute__((ext_vector_type(4)));

// Branch-free gelu via Abramowitz-Stegun 7.1.26 erf approximation (|eps|<=1.5e-7).
__device__ __forceinline__ float gelu_f(float x){
    const float z  = fabsf(x) * 0.70710678118654752440f;
    const float t  = __builtin_amdgcn_rcpf(fmaf(0.3275911f, z, 1.0f));
    const float e  = __expf(-z * z);
    float p = fmaf(t, 1.061405429f, -1.453152027f);
    p = fmaf(t, p, 1.421413741f);
    p = fmaf(t, p, -0.284496736f);
    p = fmaf(t, p, 0.254829592f);
    const float erfz = 1.0f - p * t * e;          // erf(|x|/sqrt(2))
    const float phi  = fmaf(copysignf(erfz, x), 0.5f, 0.5f);
    return x * phi;
}

// ---- stats (input x only): per (b, head, seg) partial max/sumexp/kv over 256 pos ----
// Also zeroes `pooled` (kernel boundary orders this before block2's atomics).
__global__ __launch_bounds__(256) void stats_kernel(const float* __restrict__ h,
                                                    float* __restrict__ part,
                                                    float* __restrict__ pooled){
    const int seg = blockIdx.x;
    const int hd  = blockIdx.y;
    const int b   = blockIdx.z;
    const int t   = threadIdx.x;
    const int d   = t >> 5;   // 0..7; wave-half owns one d
    const int j   = t & 31;

    if (seg == 0 && hd == 0 && b == 0){
        for (int i = t; i < B_*C_; i += 256) pooled[i] = 0.0f;
    }

    __shared__ float tile[8][SEG_];   // 8 KB
    __shared__ float sm[8];

    const float* hb = h + (size_t)b * ((size_t)C_*L_) + (size_t)(hd*DH_)*L_ + (size_t)seg*SEG_;

    for (int f = t; f < 8*SEG_/4; f += 256){
        const int row = f >> 6;            // 64 float4 per row
        const int c4  = (f & 63) << 2;
        *(f32x4*)&tile[row][c4] = *(const f32x4*)&hb[(size_t)row*L_ + c4];
    }
    __syncthreads();

    float m = -INFINITY;
    #pragma unroll
    for (int i = 0; i < SEG_/32; i++) m = fmaxf(m, tile[d][j + 32*i]);
    m = fmaxf(m, __shfl_xor(m, 1));
    m = fmaxf(m, __shfl_xor(m, 2));
    m = fmaxf(m, __shfl_xor(m, 4));
    m = fmaxf(m, __shfl_xor(m, 8));
    m = fmaxf(m, __shfl_xor(m, 16));
    if (j == 0) sm[d] = m;
    const float m_d = m;

    float s = 0.0f;
    float kv[8];
    #pragma unroll
    for (int e = 0; e < 8; e++) kv[e] = 0.0f;
    #pragma unroll
    for (int i = 0; i < SEG_/32; i++){
        const int k = j + 32*i;
        const float ek = __expf(tile[d][k] - m_d);
        s += ek;
        #pragma unroll
        for (int e = 0; e < 8; e++) kv[e] = fmaf(ek, tile[e][k], kv[e]);
    }
    s += __shfl_xor(s, 1);  s += __shfl_xor(s, 2);  s += __shfl_xor(s, 4);
    s += __shfl_xor(s, 8);  s += __shfl_xor(s, 16);
    #pragma unroll
    for (int e = 0; e < 8; e++){
        kv[e] += __shfl_xor(kv[e], 1);  kv[e] += __shfl_xor(kv[e], 2);
        kv[e] += __shfl_xor(kv[e], 4);  kv[e] += __shfl_xor(kv[e], 8);
        kv[e] += __shfl_xor(kv[e], 16);
    }
    __syncthreads();

    float* po = part + (size_t)((b*H_ + hd)*S_ + seg) * 80;
    if (j == 0){
        po[8 + d] = s;
        #pragma unroll
        for (int e = 0; e < 8; e++) po[16 + d*8 + e] = kv[e];
    }
    if (t < 8) po[t] = sm[t];
}

// ---- block: fused merge (prologue) + attention (fp32) + FC1/FC2 (f16 MFMA)
//      + fused next-block stats (epilogue) ----
// Merge prologue v2 (R9's was 3x64 serial dependent strided loads -> +29 us):
//   phase A: lane = segment; 4 coalesced f32x4 loads -> butterfly reductions
//            in registers; sc/ssum to LDS scratch (overlays uni, dead here).
//   phase B: lane = (d,e); 64 INDEPENDENT coalesced 256B kv-row loads (full
//            MLP) x LDS-broadcast sc -> fma chain.
// part is double-buffered by the caller (same-kernel read/write race).
template<bool LAST>
__global__ __launch_bounds__(256)
__attribute__((amdgpu_waves_per_eu(3, 8)))
void block_kernel(const float* hin,
                  float* hout,
                  const float* __restrict__ part_in,
                  const float* __restrict__ W1,
                  const float* __restrict__ b1,
                  const float* __restrict__ W2,
                  const float* __restrict__ b2,
                  float* __restrict__ part_out,
                  float* __restrict__ pooled){
    __shared__ __align__(16) char uni[TILE*AST*2];   // 20480 B: scratch/Ash/O16
    f16_t* Ash = (f16_t*)uni;            // [pos][k], stride AST halfs
    float* O16 = (float*)uni;            // 16 x OST floats (16640 B)
    float* scb = (float*)uni;            // merge scratch: [head][64][SCST] = 9216 B
    float* ssb = (float*)(uni + 9216);   // [head][8] ssum
    __shared__ f16_t Bsh1[32*AST];       // 2560 B: W1 as [n][k]
    __shared__ f16_t Bsh2[32*AST];       // 2560 B
    __shared__ float sb1[32], sb2[32];
    __shared__ float skv[256];           // kvn[head][d][e]
    __shared__ float pool[32];

    const int tid = threadIdx.x;
    const int b   = blockIdx.y;
    const int l0  = blockIdx.x * TILE;
    const int l   = l0 + tid;
    const size_t base = (size_t)b * ((size_t)C_*L_);

    // stage weights f32->f16 into B-layout: Bsh[n][k] = W[k*32+n]
    for (int i = tid; i < 1024; i += 256){
        const int k = i >> 5, n = i & 31;
        Bsh1[n*AST + k] = (f16_t)W1[i];
        Bsh2[n*AST + k] = (f16_t)W2[i];
    }
    if (tid < 32){ sb1[tid] = b1[tid]; sb2[tid] = b2[tid]; }
    if (LAST && tid < 32) pool[tid] = 0.0f;

    // ---- fused merge: kvn for batch b -> skv ----
    {
        const int head = tid >> 6;       // one head per wave
        const int lane = tid & 63;
        const float* p = part_in + (size_t)(b*H_ + head) * S_ * 80;

        // phase A: lane = segment s2
        const f32x4 m0 = *(const f32x4*)&p[lane*80 + 0];
        const f32x4 m1 = *(const f32x4*)&p[lane*80 + 4];
        const f32x4 s0 = *(const f32x4*)&p[lane*80 + 8];
        const f32x4 s1 = *(const f32x4*)&p[lane*80 + 12];
        const float mm[8] = {m0[0],m0[1],m0[2],m0[3],m1[0],m1[1],m1[2],m1[3]};
        const float ssv[8] = {s0[0],s0[1],s0[2],s0[3],s1[0],s1[1],s1[2],s1[3]};
        #pragma unroll
        for (int k = 0; k < 8; k++){
            float M = mm[k];
            M = fmaxf(M, __shfl_xor(M,1));  M = fmaxf(M, __shfl_xor(M,2));
            M = fmaxf(M, __shfl_xor(M,4));  M = fmaxf(M, __shfl_xor(M,8));
            M = fmaxf(M, __shfl_xor(M,16)); M = fmaxf(M, __shfl_xor(M,32));
            const float sc = __expf(mm[k] - M);
            float sv = ssv[k] * sc;
            sv += __shfl_xor(sv,1);  sv += __shfl_xor(sv,2);
            sv += __shfl_xor(sv,4);  sv += __shfl_xor(sv,8);
            sv += __shfl_xor(sv,16); sv += __shfl_xor(sv,32);
            scb[(head*64 + lane)*SCST + k] = sc;
            if (lane == 0) ssb[head*8 + k] = sv;
        }
        // phase B: lane = (d,e); same-wave LDS ops are in-order -> no barrier
        const int de = lane;
        const int dd = de >> 3;
        float kvsum = 0.f;
        #pragma unroll 16
        for (int s2 = 0; s2 < S_; s2++)
            kvsum = fmaf(p[s2*80 + 16 + de], scb[(head*64 + s2)*SCST + dd], kvsum);
        skv[head*64 + de] = kvsum * __builtin_amdgcn_rcpf(ssb[head*8 + dd]);
    }
    __syncthreads();   // skv + weights visible; scb dead (uni becomes Ash)

    // ---- phase 1: per-thread fp32 attention ----
    float h[32];
    #pragma unroll
    for (int c = 0; c < 32; c++) h[c] = hin[base + (size_t)c*L_ + l];

    float attn[32];
    #pragma unroll
    for (int hh = 0; hh < 4; hh++){
        float mq = h[hh*8];
        #pragma unroll
        for (int d2 = 1; d2 < 8; d2++) mq = fmaxf(mq, h[hh*8 + d2]);
        float es[8]; float qs = 0.f;
        #pragma unroll
        for (int d2 = 0; d2 < 8; d2++){ es[d2] = __expf(h[hh*8 + d2] - mq); qs += es[d2]; }
        const float inv = __builtin_amdgcn_rcpf(qs);
        #pragma unroll
        for (int e = 0; e < 8; e++){
            float a = 0.f;
            #pragma unroll
            for (int d2 = 0; d2 < 8; d2++) a += es[d2] * skv[hh*64 + d2*8 + e];
            attn[hh*8 + e] = a * inv;
        }
    }

    // attn -> f16 A matrix in LDS: Ash[pos=tid][k]
    #pragma unroll
    for (int k2 = 0; k2 < 32; k2 += 2){
        f16x2 pr = { (f16_t)attn[k2], (f16_t)attn[k2+1] };
        *(f16x2*)&Ash[tid*AST + k2] = pr;
    }
    __syncthreads();

    // ---- phase 2: MFMA FCs ----
    const int wv   = tid >> 6;
    const int lane = tid & 63;
    const int lr   = lane & 15;
    const int lk   = lane >> 4;
    const f32x4 zero = {0.f, 0.f, 0.f, 0.f};

    f16x8 a[4], bw[2];
    f32x4 d[8];

    // FC1
    #pragma unroll
    for (int mt = 0; mt < 4; mt++)
        a[mt] = *(const f16x8*)&Ash[(wv*64 + mt*16 + lr)*AST + lk*8];
    #pragma unroll
    for (int nt = 0; nt < 2; nt++)
        bw[nt] = *(const f16x8*)&Bsh1[(nt*16 + lr)*AST + lk*8];
    #pragma unroll
    for (int nt = 0; nt < 2; nt++)
        #pragma unroll
        for (int mt = 0; mt < 4; mt++)
            d[nt*4+mt] = __builtin_amdgcn_mfma_f32_16x16x32_f16(a[mt], bw[nt], zero, 0, 0, 0);

    // bias + gelu + write back as A2 (in-place; rows are wave-private)
    #pragma unroll
    for (int nt = 0; nt < 2; nt++){
        const float bias = sb1[nt*16 + lr];
        #pragma unroll
        for (int mt = 0; mt < 4; mt++){
            #pragma unroll
            for (int r = 0; r < 4; r++){
                const float v = gelu_f(d[nt*4+mt][r] + bias);
                Ash[(wv*64 + mt*16 + lk*4 + r)*AST + (nt*16 + lr)] = (f16_t)v;
            }
        }
    }
    __syncthreads();

    // FC2
    #pragma unroll
    for (int mt = 0; mt < 4; mt++)
        a[mt] = *(const f16x8*)&Ash[(wv*64 + mt*16 + lr)*AST + lk*8];
    #pragma unroll
    for (int nt = 0; nt < 2; nt++)
        bw[nt] = *(const f16x8*)&Bsh2[(nt*16 + lr)*AST + lk*8];
    #pragma unroll
    for (int nt = 0; nt < 2; nt++)
        #pragma unroll
        for (int mt = 0; mt < 4; mt++)
            d[nt*4+mt] = __builtin_amdgcn_mfma_f32_16x16x32_f16(a[mt], bw[nt], zero, 0, 0, 0);

    // bias + gelu on D (fp32)
    #pragma unroll
    for (int nt = 0; nt < 2; nt++){
        const float bias = sb2[nt*16 + lr];
        #pragma unroll
        for (int mt = 0; mt < 4; mt++)
            #pragma unroll
            for (int r = 0; r < 4; r++)
                d[nt*4+mt][r] = gelu_f(d[nt*4+mt][r] + bias);
    }

    if (!LAST){
        const int row16 = tid >> 4;      // 0..15: local channel row in this half
        const int grp   = tid & 15;      // 16 threads per row
        #pragma unroll
        for (int nt = 0; nt < 2; nt++){
            __syncthreads();   // Ash fully read (nt=0) / prev O16 consumed (nt=1)
            #pragma unroll
            for (int mt = 0; mt < 4; mt++)
                *(f32x4*)&O16[lr*OST + wv*64 + mt*16 + lk*4] = d[nt*4+mt];
            __syncthreads();
            #pragma unroll
            for (int c = 0; c < 16; c++)
                hout[base + (size_t)(nt*16 + c)*L_ + l0 + tid] = O16[c*OST + tid];

            // fused stats for the NEXT block: this half = heads nt*2 + {0,1}
            const int head = nt*2 + (row16 >> 3);
            const int dd   = row16 & 7;
            const float* rowD = &O16[row16*OST];
            const float* rowE = &O16[(row16 & 8)*OST];
            float m = -INFINITY;
            #pragma unroll
            for (int i = 0; i < 16; i++) m = fmaxf(m, rowD[grp + 16*i]);
            m = fmaxf(m, __shfl_xor(m, 1)); m = fmaxf(m, __shfl_xor(m, 2));
            m = fmaxf(m, __shfl_xor(m, 4)); m = fmaxf(m, __shfl_xor(m, 8));
            float s = 0.f, kvp[8];
            #pragma unroll
            for (int e = 0; e < 8; e++) kvp[e] = 0.f;
            #pragma unroll
            for (int i = 0; i < 16; i++){
                const int k = grp + 16*i;
                const float ek = __expf(rowD[k] - m);
                s += ek;
                #pragma unroll
                for (int e = 0; e < 8; e++) kvp[e] = fmaf(ek, rowE[e*OST + k], kvp[e]);
            }
            s += __shfl_xor(s, 1); s += __shfl_xor(s, 2);
            s += __shfl_xor(s, 4); s += __shfl_xor(s, 8);
            #pragma unroll
            for (int e = 0; e < 8; e++){
                kvp[e] += __shfl_xor(kvp[e], 1); kvp[e] += __shfl_xor(kvp[e], 2);
                kvp[e] += __shfl_xor(kvp[e], 4); kvp[e] += __shfl_xor(kvp[e], 8);
            }
            if (grp == 0){
                float* po = part_out + (size_t)((b*H_ + head)*S_ + blockIdx.x) * 80;
                po[dd]     = m;
                po[8 + dd] = s;
                #pragma unroll
                for (int e = 0; e < 8; e++) po[16 + dd*8 + e] = kvp[e];
            }
        }
    } else {
        __syncthreads();   // pool[] initialized
        #pragma unroll
        for (int nt = 0; nt < 2; nt++){
            float ps = 0.f;
            #pragma unroll
            for (int mt = 0; mt < 4; mt++)
                ps += d[nt*4+mt][0] + d[nt*4+mt][1] + d[nt*4+mt][2] + d[nt*4+mt][3];
            atomicAdd(&pool[nt*16 + lr], ps);
        }
        __syncthreads();
        if (tid < 32) atomicAdd(&pooled[b*32 + tid], pool[tid]);
    }
}

// ---- head: pooled/L -> Wh+bh -> BN(eval) -> gelu -> Wf+bf ----
__global__ __launch_bounds__(1024) void head_kernel(const float* __restrict__ pooled,
                                                    const float* __restrict__ Wh,
                                                    const float* __restrict__ bh,
                                                    const float* __restrict__ gam,
                                                    const float* __restrict__ bet,
                                                    const float* __restrict__ mean,
                                                    const float* __restrict__ var,
                                                    const float* __restrict__ Wf,
                                                    const float* __restrict__ bf,
                                                    float* __restrict__ out){
    __shared__ float y2[32][32];
    const int t = threadIdx.x;      // 0..1023
    const int b = t >> 5, c = t & 31;
    float a = bh[c];
    const float invL = 1.0f / (float)L_;
    #pragma unroll
    for (int d = 0; d < 32; d++) a += (pooled[b*32 + d] * invL) * Wh[d*32 + c];
    a = (a - mean[c]) * rsqrtf(var[c] + 1e-5f) * gam[c] + bet[c];
    y2[b][c] = gelu_f(a);
    __syncthreads();
    if (t < B_*DOUT_){
        const int b2 = t / DOUT_, j = t % DOUT_;
        float r = bf[j];
        #pragma unroll
        for (int c2 = 0; c2 < 32; c2++) r += y2[b2][c2] * Wf[c2*DOUT_ + j];
        out[t] = r;
    }
}

extern "C" void kernel_launch(void* const* d_in, const int* in_sizes, int n_in,
                              void* d_out, int out_size, void* d_ws, size_t ws_size,
                              hipStream_t stream){
    (void)in_sizes; (void)n_in; (void)out_size; (void)ws_size;
    const float* x    = (const float*)d_in[0];
    const float* fW1  = (const float*)d_in[1];
    const float* fb1  = (const float*)d_in[2];
    const float* fW2  = (const float*)d_in[3];
    const float* fb2  = (const float*)d_in[4];
    const float* Wh   = (const float*)d_in[5];
    const float* bh   = (const float*)d_in[6];
    const float* gam  = (const float*)d_in[7];
    const float* bet  = (const float*)d_in[8];
    const float* mean = (const float*)d_in[9];
    const float* var  = (const float*)d_in[10];
    const float* Wf   = (const float*)d_in[11];
    const float* bf   = (const float*)d_in[12];
    float* out = (float*)d_out;

    float* hbuf   = (float*)d_ws;                          // B*C*L floats (64 MB)
    float* partA  = hbuf  + (size_t)B_*C_*L_;              // B*H*S*80 (~2.6 MB)
    float* partB  = partA + (size_t)B_*H_*S_*80;           // double buffer
    float* pooled = partB + (size_t)B_*H_*S_*80;           // B*C

    dim3 sgrid(S_, H_, B_);
    dim3 bgrid(L_/TILE, B_);

    // 5-dispatch chain: stats(x) -> block0 -> block1 -> block2 -> head
    stats_kernel<<<sgrid, 256, 0, stream>>>(x, partA, pooled);
    block_kernel<false><<<bgrid, 256, 0, stream>>>(x, hbuf, partA,
        fW1, fb1, fW2, fb2, partB, nullptr);
    block_kernel<false><<<bgrid, 256, 0, stream>>>(hbuf, hbuf, partB,
        fW1 + C_*C_, fb1 + C_, fW2 + C_*C_, fb2 + C_, partA, nullptr);
    block_kernel<true><<<bgrid, 256, 0, stream>>>(hbuf, nullptr, partA,
        fW1 + 2*C_*C_, fb1 + 2*C_, fW2 + 2*C_*C_, fb2 + 2*C_, nullptr, pooled);
    head_kernel<<<1, 1024, 0, stream>>>(pooled, Wh, bh, gam, bet, mean, var, Wf, bf, out);
}